// Round 3
// baseline (251.613 us; speedup 1.0000x reference)
//
#include <hip/hip_runtime.h>
#include <hip/hip_bf16.h>
#include <stdint.h>
#include <stddef.h>

typedef __bf16 bf16;
typedef __bf16 bf16x4 __attribute__((ext_vector_type(4)));
typedef __bf16 bf16x8 __attribute__((ext_vector_type(8)));
typedef float f32x4 __attribute__((ext_vector_type(4)));

#define BATCH 4096
#define KIH 7808          // Wih K
#define KTOT 7936         // + 128 for Whh (h0 appended to x)
#define NG 512            // 4*LH gates
#define LH 128
#define HD 64
#define ED 128

// out layout: probs[B*9] | h1[B*128] | c1[B*128]
#define O_H1 (BATCH * 9)
#define O_C1 (BATCH * 9 + BATCH * LH)

// ---------------------------------------------------------------------------
// async global->LDS, 16B per lane (wave-uniform LDS base + lane*16 semantics)
// ---------------------------------------------------------------------------
typedef const __attribute__((address_space(1))) uint32_t* gas_ptr;
typedef __attribute__((address_space(3))) uint32_t* las_ptr;

__device__ __forceinline__ void async16(const void* g, void* l) {
    __builtin_amdgcn_global_load_lds((gas_ptr)g, (las_ptr)l, 16, 0, 0);
}

__device__ __forceinline__ float rl(float v, int lane) {
    return __builtin_bit_cast(float,
        __builtin_amdgcn_readlane(__builtin_bit_cast(int, v), lane));
}

// ---------------------------------------------------------------------------
// Kernel 0: pack fp32 [Wih | Whh] -> bf16 Wcat[512][7936], vectorized
// ---------------------------------------------------------------------------
__global__ void convert_w(const float* __restrict__ Wih,
                          const float* __restrict__ Whh,
                          bf16* __restrict__ Wcat) {
    const int n = blockIdx.x;           // 0..511
    const int t = threadIdx.x;          // 0..255
    const float* src_ih = Wih + (size_t)n * KIH;
    const float* src_hh = Whh + (size_t)n * LH;
    bf16* dst = Wcat + (size_t)n * KTOT;
    for (int k4 = t; k4 < KTOT / 4; k4 += 256) {
        const int k = k4 * 4;
        const float4 v = (k < KIH) ? *(const float4*)(src_ih + k)
                                   : *(const float4*)(src_hh + (k - KIH));
        bf16x4 o = {(bf16)v.x, (bf16)v.y, (bf16)v.z, (bf16)v.w};
        *(bf16x4*)(dst + k) = o;
    }
}

// ---------------------------------------------------------------------------
// Kernel 1: build x = [ab_gather | mv_gather | num @ num_W.T + num_b | h0]
// one block per batch row, 256 threads; 32 lanes per embedding slot (float4)
// ---------------------------------------------------------------------------
__global__ void build_x(const int* __restrict__ ab_ids,
                        const int* __restrict__ mv_ids,
                        const float* __restrict__ numerical,
                        const float* __restrict__ h0,
                        const float* __restrict__ ab_emb,
                        const float* __restrict__ mv_emb,
                        const float* __restrict__ numW,
                        const float* __restrict__ numb,
                        bf16* __restrict__ x) {
    const int b = blockIdx.x;
    const int t = threadIdx.x;  // 0..255
    bf16* xr = x + (size_t)b * KTOT;

    __shared__ int ids[60];
    __shared__ float numr[84];
    if (t < 60) ids[t] = (t < 12) ? ab_ids[b * 12 + t] : mv_ids[b * 48 + (t - 12)];
    if (t >= 128 && t < 128 + 84) numr[t - 128] = numerical[(size_t)b * 84 + (t - 128)];
    __syncthreads();

    const int g = t >> 5, l = t & 31;   // 8 slot-groups x 32 lanes
#pragma unroll 2
    for (int s = g; s < 60; s += 8) {
        const float* src = (s < 12) ? (ab_emb + (size_t)ids[s] * ED)
                                    : (mv_emb + (size_t)ids[s] * ED);
        const float4 v = ((const float4*)src)[l];
        bf16x4 o = {(bf16)v.x, (bf16)v.y, (bf16)v.z, (bf16)v.w};
        *(bf16x4*)(xr + s * ED + l * 4) = o;
    }

    if (t < 128) {
        float acc = numb[t];
#pragma unroll 4
        for (int k = 0; k < 84; ++k)
            acc += numr[k] * numW[t * 84 + k];
        xr[60 * ED + t] = (bf16)acc;
    } else {
        const int tt = t - 128;
        xr[KIH + tt] = (bf16)h0[(size_t)b * LH + tt];
    }
}

// ---------------------------------------------------------------------------
// Kernel 2: gates += x @ Wcat.T   (M=4096, N=512, K=7936)
// 128x128 tile, BK=64, XOR-swizzled LDS (conflict-free frag reads), split-K=8
// ---------------------------------------------------------------------------
__global__ void gemm_gates(const bf16* __restrict__ x,
                           const bf16* __restrict__ Wcat,
                           float* __restrict__ gates) {
    __shared__ bf16 As[128 * 64];
    __shared__ bf16 Bs[128 * 64];

    const int tid = threadIdx.x;
    const int w = tid >> 6;       // wave 0..3
    const int lane = tid & 63;
    const int bm = blockIdx.x;    // 0..31
    const int bn = blockIdx.y;    // 0..3
    const int bz = blockIdx.z;    // 0..7
    const int kt_beg = (bz * 124) >> 3;
    const int kt_end = ((bz + 1) * 124) >> 3;

    // staging: lane covers tile-row (lane>>3); global column chunk is XOR-
    // swizzled so that LDS slot (r, c8s) holds global chunk c8s ^ (r & 7).
    const int srow = lane >> 3;
    const int scol = ((lane & 7) ^ srow) * 8;   // global column offset (elems)

    f32x4 acc[4][4];
#pragma unroll
    for (int i = 0; i < 4; ++i)
#pragma unroll
        for (int j = 0; j < 4; ++j)
#pragma unroll
            for (int r = 0; r < 4; ++r) acc[i][j][r] = 0.f;

    const int m0 = (w & 1) * 64;   // wave's output row offset in tile
    const int n0 = (w >> 1) * 64;  // wave's output col offset in tile

    for (int kt = kt_beg; kt < kt_end; ++kt) {
        const int k0 = kt * 64;
        // ---- stage A tile (x rows) ----
#pragma unroll
        for (int j = 0; j < 4; ++j) {
            const int row = (w * 4 + j) * 8 + srow;
            const bf16* g = x + (size_t)(bm * 128 + row) * KTOT + (k0 + scol);
            async16(g, (void*)&As[((w * 4 + j) * 64 + lane) * 8]);
        }
        // ---- stage B tile (Wcat rows) ----
#pragma unroll
        for (int j = 0; j < 4; ++j) {
            const int row = (w * 4 + j) * 8 + srow;
            const bf16* g = Wcat + (size_t)(bn * 128 + row) * KTOT + (k0 + scol);
            async16(g, (void*)&Bs[((w * 4 + j) * 64 + lane) * 8]);
        }
        __syncthreads();

        // ---- compute: 2 k-steps of 32 ----
#pragma unroll
        for (int ks = 0; ks < 2; ++ks) {
            bf16x8 af[4], bfr[4];
            const int kk8 = ks * 4 + (lane >> 4);       // global column chunk
#pragma unroll
            for (int t = 0; t < 4; ++t) {
                const int m = m0 + t * 16 + (lane & 15);
                af[t] = *(const bf16x8*)&As[m * 64 + ((kk8 ^ (m & 7)) * 8)];
                const int n = n0 + t * 16 + (lane & 15);
                bfr[t] = *(const bf16x8*)&Bs[n * 64 + ((kk8 ^ (n & 7)) * 8)];
            }
#pragma unroll
            for (int ti = 0; ti < 4; ++ti)
#pragma unroll
                for (int tj = 0; tj < 4; ++tj)
                    acc[ti][tj] = __builtin_amdgcn_mfma_f32_16x16x32_bf16(
                        af[ti], bfr[tj], acc[ti][tj], 0, 0, 0);
        }
        __syncthreads();
    }

    // ---- epilogue: atomic accumulate (split-K) ----
    const int mlo = (lane >> 4) * 4;
    const int nlo = lane & 15;
#pragma unroll
    for (int ti = 0; ti < 4; ++ti)
#pragma unroll
        for (int tj = 0; tj < 4; ++tj) {
            const int mg = bm * 128 + m0 + ti * 16 + mlo;
            const int ng = bn * 128 + n0 + tj * 16 + nlo;
            float* dst = gates + (size_t)mg * NG + ng;
#pragma unroll
            for (int r = 0; r < 4; ++r)
                atomicAdd(dst + (size_t)r * NG, acc[ti][tj][r]);
        }
}

// ---------------------------------------------------------------------------
// Kernel 3: LSTM pointwise + MLP head + softmax + masked renorm
// 256 threads/block; each wave handles 4 rows; weights LDS-resident (bf16,
// additive-swizzled for conflict-free reads); h1/u broadcast via v_readlane.
// ---------------------------------------------------------------------------
__global__ __launch_bounds__(256, 1) void lstm_mlp(
    const float* __restrict__ gates, const float* __restrict__ bih,
    const float* __restrict__ bhh, const float* __restrict__ c0,
    const float* __restrict__ mask,
    const float* __restrict__ W1, const float* __restrict__ b1,
    const float* __restrict__ W2, const float* __restrict__ b2,
    const float* __restrict__ Wa, const float* __restrict__ ba,
    float* __restrict__ out) {
    __shared__ bf16 W1h[128 * 64];    // [d][(j+d)&63]        16 KB
    __shared__ bf16 W2h[64 * 128];    // [j][(t+j)&127]       16 KB
    __shared__ float Was[9 * 132];    // [a][t], padded row   4.75 KB
    __shared__ float gb[512];
    __shared__ float b1s[64];
    __shared__ float b2s[128];
    __shared__ float bas[9];
    __shared__ float mws[4][4][12];   // [wave][row][9]

    const int t = threadIdx.x;
    for (int i = t; i < 64 * 128; i += 256) {       // W1[j][d]
        const int j = i >> 7, d = i & 127;
        W1h[d * 64 + ((j + d) & 63)] = (bf16)W1[i];
    }
    for (int i = t; i < 128 * 64; i += 256) {       // W2[r][j]
        const int r = i >> 6, j = i & 63;
        W2h[j * 128 + ((r + j) & 127)] = (bf16)W2[i];
    }
    for (int i = t; i < 9 * 128; i += 256) {
        const int a = i >> 7, d = i & 127;
        Was[a * 132 + d] = Wa[i];
    }
    for (int i = t; i < 512; i += 256) gb[i] = bih[i] + bhh[i];
    if (t < 64) b1s[t] = b1[t];
    if (t < 128) b2s[t] = b2[t];
    if (t < 9) bas[t] = ba[t];
    __syncthreads();

    const int wv = t >> 6, lane = t & 63;
    const int b0 = blockIdx.x * 16 + wv * 4;

    // ---- phase 1: gates -> c1, h1 (4 rows) ----
    float h1a[4], h1b[4];
#pragma unroll
    for (int r = 0; r < 4; ++r) {
        const int b = b0 + r;
        const float* gr = gates + (size_t)b * NG;
        const float gi1 = gr[lane] + gb[lane];
        const float gi2 = gr[64 + lane] + gb[64 + lane];
        const float gf1 = gr[128 + lane] + gb[128 + lane];
        const float gf2 = gr[192 + lane] + gb[192 + lane];
        const float gg1 = gr[256 + lane] + gb[256 + lane];
        const float gg2 = gr[320 + lane] + gb[320 + lane];
        const float go1 = gr[384 + lane] + gb[384 + lane];
        const float go2 = gr[448 + lane] + gb[448 + lane];
        const float c01 = c0[(size_t)b * LH + lane];
        const float c02 = c0[(size_t)b * LH + 64 + lane];

        const float i1 = 1.f / (1.f + __expf(-gi1));
        const float i2 = 1.f / (1.f + __expf(-gi2));
        const float f1v = 1.f / (1.f + __expf(-gf1));
        const float f2v = 1.f / (1.f + __expf(-gf2));
        const float g1v = tanhf(gg1);
        const float g2v = tanhf(gg2);
        const float o1v = 1.f / (1.f + __expf(-go1));
        const float o2v = 1.f / (1.f + __expf(-go2));
        const float c11 = f1v * c01 + i1 * g1v;
        const float c12 = f2v * c02 + i2 * g2v;
        const float h11 = o1v * tanhf(c11);
        const float h12 = o2v * tanhf(c12);

        out[O_H1 + (size_t)b * LH + lane] = h11;
        out[O_H1 + (size_t)b * LH + 64 + lane] = h12;
        out[O_C1 + (size_t)b * LH + lane] = c11;
        out[O_C1 + (size_t)b * LH + 64 + lane] = c12;
        h1a[r] = h11;
        h1b[r] = h12;
        if (lane < 9) mws[wv][r][lane] = mask[(size_t)b * 9 + lane];
    }

    // ---- phase 2: u[j] = relu(b1 + sum_d h1[d] * W1[j][d]), j = lane ----
    float u[4] = {b1s[lane], b1s[lane], b1s[lane], b1s[lane]};
#pragma unroll
    for (int d = 0; d < 64; ++d) {
        const float wv1 = (float)W1h[d * 64 + ((lane + d) & 63)];
        u[0] += rl(h1a[0], d) * wv1;
        u[1] += rl(h1a[1], d) * wv1;
        u[2] += rl(h1a[2], d) * wv1;
        u[3] += rl(h1a[3], d) * wv1;
    }
#pragma unroll
    for (int d = 64; d < 128; ++d) {
        const float wv1 = (float)W1h[d * 64 + ((lane + d) & 63)];
        u[0] += rl(h1b[0], d - 64) * wv1;
        u[1] += rl(h1b[1], d - 64) * wv1;
        u[2] += rl(h1b[2], d - 64) * wv1;
        u[3] += rl(h1b[3], d - 64) * wv1;
    }
#pragma unroll
    for (int r = 0; r < 4; ++r) u[r] = fmaxf(u[r], 0.f);

    // ---- phase 3: feat[t] = b2 + sum_j u[j] * W2[t][j]; t1=lane, t2=64+lane
    float f1[4] = {b2s[lane], b2s[lane], b2s[lane], b2s[lane]};
    float f2[4] = {b2s[64 + lane], b2s[64 + lane], b2s[64 + lane], b2s[64 + lane]};
#pragma unroll
    for (int j = 0; j < 64; ++j) {
        const float w2a = (float)W2h[j * 128 + ((lane + j) & 127)];
        const float w2b = (float)W2h[j * 128 + ((64 + lane + j) & 127)];
#pragma unroll
        for (int r = 0; r < 4; ++r) {
            const float uj = rl(u[r], j);
            f1[r] += uj * w2a;
            f2[r] += uj * w2b;
        }
    }

    // ---- phase 4: logits partials + wave reduction ----
    float p[4][9];
#pragma unroll
    for (int r = 0; r < 4; ++r)
#pragma unroll
        for (int a = 0; a < 9; ++a)
            p[r][a] = f1[r] * Was[a * 132 + lane] + f2[r] * Was[a * 132 + 64 + lane];
#pragma unroll
    for (int off = 1; off < 64; off <<= 1)
#pragma unroll
        for (int r = 0; r < 4; ++r)
#pragma unroll
            for (int a = 0; a < 9; ++a)
                p[r][a] += __shfl_xor(p[r][a], off, 64);

    asm volatile("s_waitcnt lgkmcnt(0)" ::: "memory");  // mws visibility

    // ---- softmax + masked renorm (per-lane redundant over 9 logits) ----
#pragma unroll
    for (int r = 0; r < 4; ++r) {
        float lg[9], mx = -1e30f;
#pragma unroll
        for (int a = 0; a < 9; ++a) {
            lg[a] = p[r][a] + bas[a];
            mx = fmaxf(mx, lg[a]);
        }
        float es[9], tot = 0.f, ms = 0.f;
#pragma unroll
        for (int a = 0; a < 9; ++a) {
            es[a] = __expf(lg[a] - mx);
            tot += es[a];
            ms += es[a] * mws[wv][r][a];
        }
        const int b = b0 + r;
        if (lane < 9) {
            const float mv = mws[wv][r][lane];
            out[(size_t)b * 9 + lane] =
                (ms > 0.f) ? es[lane] * mv / ms : es[lane] / tot;
        }
    }
}

// ---------------------------------------------------------------------------
extern "C" void kernel_launch(void* const* d_in, const int* in_sizes, int n_in,
                              void* d_out, int out_size, void* d_ws, size_t ws_size,
                              hipStream_t stream) {
    const int* ab_ids = (const int*)d_in[0];
    const int* mv_ids = (const int*)d_in[1];
    const float* numerical = (const float*)d_in[2];
    const float* mask = (const float*)d_in[3];
    const float* h0 = (const float*)d_in[4];
    const float* c0 = (const float*)d_in[5];
    const float* ab_emb = (const float*)d_in[6];
    const float* mv_emb = (const float*)d_in[7];
    const float* numW = (const float*)d_in[8];
    const float* numb = (const float*)d_in[9];
    const float* Wih = (const float*)d_in[10];
    const float* Whh = (const float*)d_in[11];
    const float* bih = (const float*)d_in[12];
    const float* bhh = (const float*)d_in[13];
    const float* W1 = (const float*)d_in[14];
    const float* b1 = (const float*)d_in[15];
    const float* W2 = (const float*)d_in[16];
    const float* b2 = (const float*)d_in[17];
    const float* Wa = (const float*)d_in[18];
    const float* ba = (const float*)d_in[19];
    float* out = (float*)d_out;

    char* ws = (char*)d_ws;
    bf16* x = (bf16*)ws;                                  // 65,011,712 B
    bf16* Wcat = (bf16*)(ws + (size_t)65011712);          //  8,126,464 B
    float* gates = (float*)(ws + (size_t)73138176);       //  8,388,608 B

    hipMemsetAsync(gates, 0, (size_t)BATCH * NG * sizeof(float), stream);
    convert_w<<<512, 256, 0, stream>>>(Wih, Whh, Wcat);
    build_x<<<BATCH, 256, 0, stream>>>(ab_ids, mv_ids, numerical, h0,
                                       ab_emb, mv_emb, numW, numb, x);
    gemm_gates<<<dim3(32, 4, 8), 256, 0, stream>>>(x, Wcat, gates);
    lstm_mlp<<<256, 256, 0, stream>>>(gates, bih, bhh, c0, mask,
                                      W1, b1, W2, b2, Wa, ba, out);
}

// Round 5
// 236.379 us; speedup vs baseline: 1.0644x; 1.0644x over previous
//
#include <hip/hip_runtime.h>
#include <hip/hip_bf16.h>
#include <stdint.h>
#include <stddef.h>

typedef __bf16 bf16;
typedef __bf16 bf16x8 __attribute__((ext_vector_type(8)));
typedef float f32x4 __attribute__((ext_vector_type(4)));

#define BATCH 4096
#define KIH 7808          // Wih K
#define KTOT 7936         // 62 slots * 128 (h0 appended)
#define NG 512            // 4*LH gates
#define LH 128
#define HD 64
#define ED 128

// workspace layout (byte offsets)
#define OFF_WCAT 0u                 //  8,126,464  bf16 Wcat[512][7936]
#define OFF_GATES 8126464u          //  8,388,608  f32 gates[4096][512]
#define OFF_XT   16515072u          //  2,097,152  bf16 xtail[4096][256] (numproj|h0)
#define OFF_AB   18612224u          //     76,800  bf16 ab8[300][128]
#define OFF_MV   18689024u          //    230,400  bf16 mv8[900][128]
#define OFF_ADDR 18919424u          //  2,097,152  u32 addrs[4096][64]

// out layout: probs[B*9] | h1[B*128] | c1[B*128]
#define O_H1 (BATCH * 9)
#define O_C1 (BATCH * 9 + BATCH * LH)

// ---------------------------------------------------------------------------
typedef const __attribute__((address_space(1))) uint32_t* gas_ptr;
typedef __attribute__((address_space(3))) uint32_t* las_ptr;

__device__ __forceinline__ void async16(const void* g, void* l) {
    __builtin_amdgcn_global_load_lds((gas_ptr)g, (las_ptr)l, 16, 0, 0);
}

__device__ __forceinline__ float rl(float v, int lane) {
    return __builtin_bit_cast(float,
        __builtin_amdgcn_readlane(__builtin_bit_cast(int, v), lane));
}

// ---------------------------------------------------------------------------
// Kernel 0a: pack fp32 [Wih | Whh] -> bf16 Wcat[512][7936]
// ---------------------------------------------------------------------------
__global__ void convert_w(const float* __restrict__ Wih,
                          const float* __restrict__ Whh,
                          bf16* __restrict__ Wcat) {
    const int n = blockIdx.x;           // 0..511
    const int t = threadIdx.x;          // 0..255
    const float* src_ih = Wih + (size_t)n * KIH;
    const float* src_hh = Whh + (size_t)n * LH;
    bf16* dst = Wcat + (size_t)n * KTOT;
    for (int k4 = t; k4 < KTOT / 4; k4 += 256) {
        const int k = k4 * 4;
        const float4 v = (k < KIH) ? *(const float4*)(src_ih + k)
                                   : *(const float4*)(src_hh + (k - KIH));
        bf16 o0 = (bf16)v.x, o1 = (bf16)v.y, o2 = (bf16)v.z, o3 = (bf16)v.w;
        dst[k] = o0; dst[k + 1] = o1; dst[k + 2] = o2; dst[k + 3] = o3;
    }
}

// ---------------------------------------------------------------------------
// Kernel 0b: fp32 embedding tables -> bf16 (L2-resident gather sources)
// ---------------------------------------------------------------------------
__global__ void convert_emb(const float* __restrict__ ab_emb,
                            const float* __restrict__ mv_emb,
                            bf16* __restrict__ ab8,
                            bf16* __restrict__ mv8) {
    const int i = blockIdx.x * 256 + threadIdx.x;   // 0..153599
    if (i < 300 * 128) ab8[i] = (bf16)ab_emb[i];
    else mv8[i - 300 * 128] = (bf16)mv_emb[i - 300 * 128];
}

// ---------------------------------------------------------------------------
// Kernel 0c: per-row slot offsets + xtail = [numproj | h0] (bf16)
// one block per batch row, 256 threads
// ---------------------------------------------------------------------------
__global__ void build_pre(const int* __restrict__ ab_ids,
                          const int* __restrict__ mv_ids,
                          const float* __restrict__ numerical,
                          const float* __restrict__ h0,
                          const float* __restrict__ numW,
                          const float* __restrict__ numb,
                          bf16* __restrict__ xtail,
                          uint32_t* __restrict__ addrs) {
    const int b = blockIdx.x;
    const int t = threadIdx.x;  // 0..255

    __shared__ int ids[60];
    __shared__ float numr[84];
    if (t < 60) ids[t] = (t < 12) ? ab_ids[b * 12 + t] : mv_ids[b * 48 + (t - 12)];
    if (t >= 128 && t < 128 + 84) numr[t - 128] = numerical[(size_t)b * 84 + (t - 128)];
    __syncthreads();

    if (t < 128) {
        float acc = numb[t];
#pragma unroll 4
        for (int k = 0; k < 84; ++k)
            acc += numr[k] * numW[t * 84 + k];
        xtail[(size_t)b * 256 + t] = (bf16)acc;
    } else {
        const int tt = t - 128;
        xtail[(size_t)b * 256 + 128 + tt] = (bf16)h0[(size_t)b * LH + tt];
    }

    if (t < 64) {
        uint32_t off;
        if (t < 12) off = OFF_AB + (uint32_t)ids[t] * 256u;
        else if (t < 60) off = OFF_MV + (uint32_t)ids[t] * 256u;
        else if (t == 60) off = OFF_XT + (uint32_t)b * 512u;
        else if (t == 61) off = OFF_XT + (uint32_t)b * 512u + 256u;
        else off = OFF_XT;  // unused slots 62,63
        addrs[(size_t)b * 64 + t] = off;
    }
}

// ---------------------------------------------------------------------------
// Kernel 2: gates += x @ Wcat.T  (x gathered on the fly; M=4096,N=512,K=7936)
// 128x128 tile, BK=64, XOR-swizzled LDS, split-K=8; A staged straight from
// bf16 tables via per-(row,slot) offsets (all L2-resident).
// ---------------------------------------------------------------------------
__global__ void gemm_gates(const uint8_t* __restrict__ wsbase,
                           const bf16* __restrict__ Wcat,
                           const uint32_t* __restrict__ addrs,
                           float* __restrict__ gates) {
    __shared__ bf16 As[128 * 64];       // 16 KB
    __shared__ bf16 Bs[128 * 64];       // 16 KB
    __shared__ uint32_t adr[9][128];    // 4.5 KB: slot-local offsets

    const int tid = threadIdx.x;
    const int w = tid >> 6;       // wave 0..3
    const int lane = tid & 63;
    const int bm = blockIdx.x;    // 0..31
    const int bn = blockIdx.y;    // 0..3
    const int bz = blockIdx.z;    // 0..7
    const int kt_beg = (bz * 124) >> 3;
    const int kt_end = ((bz + 1) * 124) >> 3;

    // preload this block's (row, slot) offsets
    const int s0 = kt_beg >> 1;
    const int ns = ((kt_end - 1) >> 1) - s0 + 1;   // <= 9
    for (int i = tid; i < ns * 128; i += 256) {
        adr[i >> 7][i & 127] =
            addrs[(size_t)(bm * 128 + (i & 127)) * 64 + s0 + (i >> 7)];
    }

    const int r_l = lane >> 3;                  // staging row within 8-row group
    const int sc16 = ((lane & 7) ^ r_l) * 16;   // XOR-swizzled 16B chunk (bytes)

    f32x4 acc[4][4];
#pragma unroll
    for (int i = 0; i < 4; ++i)
#pragma unroll
        for (int j = 0; j < 4; ++j)
#pragma unroll
            for (int r = 0; r < 4; ++r) acc[i][j][r] = 0.f;

    const int m0 = (w & 1) * 64;
    const int n0 = (w >> 1) * 64;

    __syncthreads();  // adr ready

    for (int kt = kt_beg; kt < kt_end; ++kt) {
        const int k0 = kt * 64;
        const int sl = (kt >> 1) - s0;          // slot-local index
        const int hb = (kt & 1) * 128;          // byte offset within slot
        // ---- stage A tile: gather from tables ----
#pragma unroll
        for (int j = 0; j < 4; ++j) {
            const int row = (w * 4 + j) * 8 + r_l;
            const uint8_t* gsrc = wsbase + adr[sl][row] + hb + sc16;
            async16(gsrc, (void*)&As[((w * 4 + j) * 64 + lane) * 8]);
        }
        // ---- stage B tile (Wcat rows) ----
#pragma unroll
        for (int j = 0; j < 4; ++j) {
            const int row = (w * 4 + j) * 8 + r_l;
            const bf16* gsrc = Wcat + (size_t)(bn * 128 + row) * KTOT + k0 + (sc16 >> 1);
            async16(gsrc, (void*)&Bs[((w * 4 + j) * 64 + lane) * 8]);
        }
        __syncthreads();

        // ---- compute: 2 k-steps of 32 ----
#pragma unroll
        for (int ks = 0; ks < 2; ++ks) {
            bf16x8 af[4], bfr[4];
            const int kk8 = ks * 4 + (lane >> 4);       // global column chunk
#pragma unroll
            for (int t = 0; t < 4; ++t) {
                const int m = m0 + t * 16 + (lane & 15);
                af[t] = *(const bf16x8*)&As[m * 64 + ((kk8 ^ (m & 7)) * 8)];
                const int n = n0 + t * 16 + (lane & 15);
                bfr[t] = *(const bf16x8*)&Bs[n * 64 + ((kk8 ^ (n & 7)) * 8)];
            }
#pragma unroll
            for (int ti = 0; ti < 4; ++ti)
#pragma unroll
                for (int tj = 0; tj < 4; ++tj)
                    acc[ti][tj] = __builtin_amdgcn_mfma_f32_16x16x32_bf16(
                        af[ti], bfr[tj], acc[ti][tj], 0, 0, 0);
        }
        __syncthreads();
    }

    // ---- epilogue: atomic accumulate (split-K) ----
    const int mlo = (lane >> 4) * 4;
    const int nlo = lane & 15;
#pragma unroll
    for (int ti = 0; ti < 4; ++ti)
#pragma unroll
        for (int tj = 0; tj < 4; ++tj) {
            const int mg = bm * 128 + m0 + ti * 16 + mlo;
            const int ng = bn * 128 + n0 + tj * 16 + nlo;
            float* dst = gates + (size_t)mg * NG + ng;
#pragma unroll
            for (int r = 0; r < 4; ++r)
                atomicAdd(dst + (size_t)r * NG, acc[ti][tj][r]);
        }
}

// ---------------------------------------------------------------------------
// Kernel 3: LSTM pointwise + MLP head + softmax + masked renorm
// 256 threads/block; each wave handles 4 rows; weights LDS-resident (bf16,
// additive-swizzled); h1/u broadcast via v_readlane.  (verbatim round 3)
// ---------------------------------------------------------------------------
__global__ __launch_bounds__(256, 1) void lstm_mlp(
    const float* __restrict__ gates, const float* __restrict__ bih,
    const float* __restrict__ bhh, const float* __restrict__ c0,
    const float* __restrict__ mask,
    const float* __restrict__ W1, const float* __restrict__ b1,
    const float* __restrict__ W2, const float* __restrict__ b2,
    const float* __restrict__ Wa, const float* __restrict__ ba,
    float* __restrict__ out) {
    __shared__ bf16 W1h[128 * 64];
    __shared__ bf16 W2h[64 * 128];
    __shared__ float Was[9 * 132];
    __shared__ float gb[512];
    __shared__ float b1s[64];
    __shared__ float b2s[128];
    __shared__ float bas[9];
    __shared__ float mws[4][4][12];

    const int t = threadIdx.x;
    for (int i = t; i < 64 * 128; i += 256) {
        const int j = i >> 7, d = i & 127;
        W1h[d * 64 + ((j + d) & 63)] = (bf16)W1[i];
    }
    for (int i = t; i < 128 * 64; i += 256) {
        const int r = i >> 6, j = i & 63;
        W2h[j * 128 + ((r + j) & 127)] = (bf16)W2[i];
    }
    for (int i = t; i < 9 * 128; i += 256) {
        const int a = i >> 7, d = i & 127;
        Was[a * 132 + d] = Wa[i];
    }
    for (int i = t; i < 512; i += 256) gb[i] = bih[i] + bhh[i];
    if (t < 64) b1s[t] = b1[t];
    if (t < 128) b2s[t] = b2[t];
    if (t < 9) bas[t] = ba[t];
    __syncthreads();

    const int wv = t >> 6, lane = t & 63;
    const int b0 = blockIdx.x * 16 + wv * 4;

    float h1a[4], h1b[4];
#pragma unroll
    for (int r = 0; r < 4; ++r) {
        const int b = b0 + r;
        const float* gr = gates + (size_t)b * NG;
        const float gi1 = gr[lane] + gb[lane];
        const float gi2 = gr[64 + lane] + gb[64 + lane];
        const float gf1 = gr[128 + lane] + gb[128 + lane];
        const float gf2 = gr[192 + lane] + gb[192 + lane];
        const float gg1 = gr[256 + lane] + gb[256 + lane];
        const float gg2 = gr[320 + lane] + gb[320 + lane];
        const float go1 = gr[384 + lane] + gb[384 + lane];
        const float go2 = gr[448 + lane] + gb[448 + lane];
        const float c01 = c0[(size_t)b * LH + lane];
        const float c02 = c0[(size_t)b * LH + 64 + lane];

        const float i1 = 1.f / (1.f + __expf(-gi1));
        const float i2 = 1.f / (1.f + __expf(-gi2));
        const float f1v = 1.f / (1.f + __expf(-gf1));
        const float f2v = 1.f / (1.f + __expf(-gf2));
        const float g1v = tanhf(gg1);
        const float g2v = tanhf(gg2);
        const float o1v = 1.f / (1.f + __expf(-go1));
        const float o2v = 1.f / (1.f + __expf(-go2));
        const float c11 = f1v * c01 + i1 * g1v;
        const float c12 = f2v * c02 + i2 * g2v;
        const float h11 = o1v * tanhf(c11);
        const float h12 = o2v * tanhf(c12);

        out[O_H1 + (size_t)b * LH + lane] = h11;
        out[O_H1 + (size_t)b * LH + 64 + lane] = h12;
        out[O_C1 + (size_t)b * LH + lane] = c11;
        out[O_C1 + (size_t)b * LH + 64 + lane] = c12;
        h1a[r] = h11;
        h1b[r] = h12;
        if (lane < 9) mws[wv][r][lane] = mask[(size_t)b * 9 + lane];
    }

    float u[4] = {b1s[lane], b1s[lane], b1s[lane], b1s[lane]};
#pragma unroll
    for (int d = 0; d < 64; ++d) {
        const float wv1 = (float)W1h[d * 64 + ((lane + d) & 63)];
        u[0] += rl(h1a[0], d) * wv1;
        u[1] += rl(h1a[1], d) * wv1;
        u[2] += rl(h1a[2], d) * wv1;
        u[3] += rl(h1a[3], d) * wv1;
    }
#pragma unroll
    for (int d = 64; d < 128; ++d) {
        const float wv1 = (float)W1h[d * 64 + ((lane + d) & 63)];
        u[0] += rl(h1b[0], d - 64) * wv1;
        u[1] += rl(h1b[1], d - 64) * wv1;
        u[2] += rl(h1b[2], d - 64) * wv1;
        u[3] += rl(h1b[3], d - 64) * wv1;
    }
#pragma unroll
    for (int r = 0; r < 4; ++r) u[r] = fmaxf(u[r], 0.f);

    float f1[4] = {b2s[lane], b2s[lane], b2s[lane], b2s[lane]};
    float f2[4] = {b2s[64 + lane], b2s[64 + lane], b2s[64 + lane], b2s[64 + lane]};
#pragma unroll
    for (int j = 0; j < 64; ++j) {
        const float w2a = (float)W2h[j * 128 + ((lane + j) & 127)];
        const float w2b = (float)W2h[j * 128 + ((64 + lane + j) & 127)];
#pragma unroll
        for (int r = 0; r < 4; ++r) {
            const float uj = rl(u[r], j);
            f1[r] += uj * w2a;
            f2[r] += uj * w2b;
        }
    }

    float p[4][9];
#pragma unroll
    for (int r = 0; r < 4; ++r)
#pragma unroll
        for (int a = 0; a < 9; ++a)
            p[r][a] = f1[r] * Was[a * 132 + lane] + f2[r] * Was[a * 132 + 64 + lane];
#pragma unroll
    for (int off = 1; off < 64; off <<= 1)
#pragma unroll
        for (int r = 0; r < 4; ++r)
#pragma unroll
            for (int a = 0; a < 9; ++a)
                p[r][a] += __shfl_xor(p[r][a], off, 64);

    asm volatile("s_waitcnt lgkmcnt(0)" ::: "memory");

#pragma unroll
    for (int r = 0; r < 4; ++r) {
        float lg[9], mx = -1e30f;
#pragma unroll
        for (int a = 0; a < 9; ++a) {
            lg[a] = p[r][a] + bas[a];
            mx = fmaxf(mx, lg[a]);
        }
        float es[9], tot = 0.f, ms = 0.f;
#pragma unroll
        for (int a = 0; a < 9; ++a) {
            es[a] = __expf(lg[a] - mx);
            tot += es[a];
            ms += es[a] * mws[wv][r][a];
        }
        const int b = b0 + r;
        if (lane < 9) {
            const float mv = mws[wv][r][lane];
            out[(size_t)b * 9 + lane] =
                (ms > 0.f) ? es[lane] * mv / ms : es[lane] / tot;
        }
    }
}

// ---------------------------------------------------------------------------
extern "C" void kernel_launch(void* const* d_in, const int* in_sizes, int n_in,
                              void* d_out, int out_size, void* d_ws, size_t ws_size,
                              hipStream_t stream) {
    const int* ab_ids = (const int*)d_in[0];
    const int* mv_ids = (const int*)d_in[1];
    const float* numerical = (const float*)d_in[2];
    const float* mask = (const float*)d_in[3];
    const float* h0 = (const float*)d_in[4];
    const float* c0 = (const float*)d_in[5];
    const float* ab_emb = (const float*)d_in[6];
    const float* mv_emb = (const float*)d_in[7];
    const float* numW = (const float*)d_in[8];
    const float* numb = (const float*)d_in[9];
    const float* Wih = (const float*)d_in[10];
    const float* Whh = (const float*)d_in[11];
    const float* bih = (const float*)d_in[12];
    const float* bhh = (const float*)d_in[13];
    const float* W1 = (const float*)d_in[14];
    const float* b1 = (const float*)d_in[15];
    const float* W2 = (const float*)d_in[16];
    const float* b2 = (const float*)d_in[17];
    const float* Wa = (const float*)d_in[18];
    const float* ba = (const float*)d_in[19];
    float* out = (float*)d_out;

    uint8_t* ws = (uint8_t*)d_ws;
    bf16* Wcat = (bf16*)(ws + OFF_WCAT);
    float* gates = (float*)(ws + OFF_GATES);
    bf16* xtail = (bf16*)(ws + OFF_XT);
    bf16* ab8 = (bf16*)(ws + OFF_AB);
    bf16* mv8 = (bf16*)(ws + OFF_MV);
    uint32_t* addrs = (uint32_t*)(ws + OFF_ADDR);

    hipMemsetAsync(gates, 0, (size_t)BATCH * NG * sizeof(float), stream);
    convert_w<<<512, 256, 0, stream>>>(Wih, Whh, Wcat);
    convert_emb<<<600, 256, 0, stream>>>(ab_emb, mv_emb, ab8, mv8);
    build_pre<<<BATCH, 256, 0, stream>>>(ab_ids, mv_ids, numerical, h0,
                                         numW, numb, xtail, addrs);
    gemm_gates<<<dim3(32, 4, 8), 256, 0, stream>>>(ws, Wcat, addrs, gates);
    lstm_mlp<<<256, 256, 0, stream>>>(gates, bih, bhh, c0, mask,
                                      W1, b1, W2, b2, Wa, ba, out);
}

// Round 6
// 209.625 us; speedup vs baseline: 1.2003x; 1.1276x over previous
//
#include <hip/hip_runtime.h>
#include <hip/hip_bf16.h>
#include <stdint.h>
#include <stddef.h>

typedef __bf16 bf16;
typedef __bf16 bf16x8 __attribute__((ext_vector_type(8)));
typedef float f32x4 __attribute__((ext_vector_type(4)));

#define BATCH 4096
#define KIH 7808          // Wih K
#define KTOT 7936         // 62 slots * 128 (h0 appended)
#define NG 512            // 4*LH gates
#define LH 128
#define HD 64
#define ED 128
#define SPLITK 8

// workspace layout (byte offsets)
#define OFF_WCAT 0u                 //  8,126,464  bf16 Wcat[512][7936]
#define OFF_GPART 8126464u          // 67,108,864  f32 gpart[8][4096][512]
#define OFF_XT   75235328u          //  2,097,152  bf16 xtail[4096][256] (numproj|h0)
#define OFF_AB   77332480u          //     76,800  bf16 ab8[300][128]
#define OFF_MV   77409280u          //    230,400  bf16 mv8[900][128]
#define OFF_ADDR 77639680u          //  2,097,152  u32 addrs[4096][64]
// end: 79,736,832 B

// out layout: probs[B*9] | h1[B*128] | c1[B*128]
#define O_H1 (BATCH * 9)
#define O_C1 (BATCH * 9 + BATCH * LH)

// ---------------------------------------------------------------------------
typedef const __attribute__((address_space(1))) uint32_t* gas_ptr;
typedef __attribute__((address_space(3))) uint32_t* las_ptr;

__device__ __forceinline__ void async16(const void* g, void* l) {
    __builtin_amdgcn_global_load_lds((gas_ptr)g, (las_ptr)l, 16, 0, 0);
}

__device__ __forceinline__ float rl(float v, int lane) {
    return __builtin_bit_cast(float,
        __builtin_amdgcn_readlane(__builtin_bit_cast(int, v), lane));
}

// ---------------------------------------------------------------------------
// Kernel 0a: pack fp32 [Wih | Whh] -> bf16 Wcat[512][7936]
// ---------------------------------------------------------------------------
__global__ void convert_w(const float* __restrict__ Wih,
                          const float* __restrict__ Whh,
                          bf16* __restrict__ Wcat) {
    const int n = blockIdx.x;           // 0..511
    const int t = threadIdx.x;          // 0..255
    const float* src_ih = Wih + (size_t)n * KIH;
    const float* src_hh = Whh + (size_t)n * LH;
    bf16* dst = Wcat + (size_t)n * KTOT;
    for (int k4 = t; k4 < KTOT / 4; k4 += 256) {
        const int k = k4 * 4;
        const float4 v = (k < KIH) ? *(const float4*)(src_ih + k)
                                   : *(const float4*)(src_hh + (k - KIH));
        bf16 o0 = (bf16)v.x, o1 = (bf16)v.y, o2 = (bf16)v.z, o3 = (bf16)v.w;
        dst[k] = o0; dst[k + 1] = o1; dst[k + 2] = o2; dst[k + 3] = o3;
    }
}

// ---------------------------------------------------------------------------
// Kernel 0b: fp32 embedding tables -> bf16 (L2-resident gather sources)
// ---------------------------------------------------------------------------
__global__ void convert_emb(const float* __restrict__ ab_emb,
                            const float* __restrict__ mv_emb,
                            bf16* __restrict__ ab8,
                            bf16* __restrict__ mv8) {
    const int i = blockIdx.x * 256 + threadIdx.x;   // 0..153599
    if (i < 300 * 128) ab8[i] = (bf16)ab_emb[i];
    else mv8[i - 300 * 128] = (bf16)mv_emb[i - 300 * 128];
}

// ---------------------------------------------------------------------------
// Kernel 0c: per-row slot offsets + xtail = [numproj | h0] (bf16)
// ---------------------------------------------------------------------------
__global__ void build_pre(const int* __restrict__ ab_ids,
                          const int* __restrict__ mv_ids,
                          const float* __restrict__ numerical,
                          const float* __restrict__ h0,
                          const float* __restrict__ numW,
                          const float* __restrict__ numb,
                          bf16* __restrict__ xtail,
                          uint32_t* __restrict__ addrs) {
    const int b = blockIdx.x;
    const int t = threadIdx.x;  // 0..255

    __shared__ int ids[60];
    __shared__ float numr[84];
    if (t < 60) ids[t] = (t < 12) ? ab_ids[b * 12 + t] : mv_ids[b * 48 + (t - 12)];
    if (t >= 128 && t < 128 + 84) numr[t - 128] = numerical[(size_t)b * 84 + (t - 128)];
    __syncthreads();

    if (t < 128) {
        float acc = numb[t];
#pragma unroll 4
        for (int k = 0; k < 84; ++k)
            acc += numr[k] * numW[t * 84 + k];
        xtail[(size_t)b * 256 + t] = (bf16)acc;
    } else {
        const int tt = t - 128;
        xtail[(size_t)b * 256 + 128 + tt] = (bf16)h0[(size_t)b * LH + tt];
    }

    if (t < 64) {
        uint32_t off;
        if (t < 12) off = OFF_AB + (uint32_t)ids[t] * 256u;
        else if (t < 60) off = OFF_MV + (uint32_t)ids[t] * 256u;
        else if (t == 60) off = OFF_XT + (uint32_t)b * 512u;
        else if (t == 61) off = OFF_XT + (uint32_t)b * 512u + 256u;
        else off = OFF_XT;  // unused slots 62,63
        addrs[(size_t)b * 64 + t] = off;
    }
}

// ---------------------------------------------------------------------------
// Kernel 2: gpart[bz] = x @ Wcat.T partial  (x gathered on the fly)
// 128x128 tile, BK=64, XOR-swizzled LDS, DOUBLE-BUFFERED staging,
// split-K=8 with plain-store partials (no atomics).
// ---------------------------------------------------------------------------
__global__ __launch_bounds__(256, 2) void gemm_gates(
    const uint8_t* __restrict__ wsbase,
    const bf16* __restrict__ Wcat,
    const uint32_t* __restrict__ addrs,
    float* __restrict__ gpart) {
    __shared__ bf16 As[2][128 * 64];    // 2 x 16 KB
    __shared__ bf16 Bs[2][128 * 64];    // 2 x 16 KB
    __shared__ uint32_t adr[9][128];    // 4.5 KB

    const int tid = threadIdx.x;
    const int w = tid >> 6;       // wave 0..3
    const int lane = tid & 63;
    const int bm = blockIdx.x;    // 0..31
    const int bn = blockIdx.y;    // 0..3
    const int bz = blockIdx.z;    // 0..7
    const int kt_beg = (bz * 124) >> 3;
    const int kt_end = ((bz + 1) * 124) >> 3;

    // preload this block's (row, slot) offsets
    const int s0 = kt_beg >> 1;
    const int ns = ((kt_end - 1) >> 1) - s0 + 1;   // <= 9
    for (int i = tid; i < ns * 128; i += 256) {
        adr[i >> 7][i & 127] =
            addrs[(size_t)(bm * 128 + (i & 127)) * 64 + s0 + (i >> 7)];
    }

    const int r_l = lane >> 3;                  // staging row within 8-row group
    const int sc16 = ((lane & 7) ^ r_l) * 16;   // XOR-swizzled 16B chunk (bytes)

    f32x4 acc[4][4];
#pragma unroll
    for (int i = 0; i < 4; ++i)
#pragma unroll
        for (int j = 0; j < 4; ++j)
#pragma unroll
            for (int r = 0; r < 4; ++r) acc[i][j][r] = 0.f;

    const int m0 = (w & 1) * 64;
    const int n0 = (w >> 1) * 64;

    __syncthreads();  // adr visible

    // ---- staging helper ----
    auto stage = [&](int kt, int pb) {
        const int k0 = kt * 64;
        const int sl = (kt >> 1) - s0;
        const int hb = (kt & 1) * 128;
#pragma unroll
        for (int j = 0; j < 4; ++j) {
            const int row = (w * 4 + j) * 8 + r_l;
            const uint8_t* gsrc = wsbase + adr[sl][row] + hb + sc16;
            async16(gsrc, (void*)&As[pb][((w * 4 + j) * 64 + lane) * 8]);
        }
#pragma unroll
        for (int j = 0; j < 4; ++j) {
            const int row = (w * 4 + j) * 8 + r_l;
            const bf16* gsrc = Wcat + (size_t)(bn * 128 + row) * KTOT + k0 + (sc16 >> 1);
            async16(gsrc, (void*)&Bs[pb][((w * 4 + j) * 64 + lane) * 8]);
        }
    };

    stage(kt_beg, 0);   // prologue into buffer 0

    for (int kt = kt_beg; kt < kt_end; ++kt) {
        const int pb = (kt - kt_beg) & 1;
        // Drains each wave's own outstanding DMAs (those targeting pb, issued
        // one full iteration ago) + synchronizes; pb^1's DMAs aren't issued yet.
        __syncthreads();
        if (kt + 1 < kt_end) stage(kt + 1, pb ^ 1);

        const bf16* Ab = &As[pb][0];
        const bf16* Bb = &Bs[pb][0];
        // ---- compute: 2 k-steps of 32 on buffer pb ----
#pragma unroll
        for (int ks = 0; ks < 2; ++ks) {
            bf16x8 af[4], bfr[4];
            const int kk8 = ks * 4 + (lane >> 4);       // global column chunk
#pragma unroll
            for (int t = 0; t < 4; ++t) {
                const int m = m0 + t * 16 + (lane & 15);
                af[t] = *(const bf16x8*)&Ab[m * 64 + ((kk8 ^ (m & 7)) * 8)];
                const int n = n0 + t * 16 + (lane & 15);
                bfr[t] = *(const bf16x8*)&Bb[n * 64 + ((kk8 ^ (n & 7)) * 8)];
            }
#pragma unroll
            for (int ti = 0; ti < 4; ++ti)
#pragma unroll
                for (int tj = 0; tj < 4; ++tj)
                    acc[ti][tj] = __builtin_amdgcn_mfma_f32_16x16x32_bf16(
                        af[ti], bfr[tj], acc[ti][tj], 0, 0, 0);
        }
    }

    // ---- epilogue: plain stores to this bz's partial buffer ----
    float* gdst = gpart + (size_t)bz * BATCH * NG;
    const int mlo = (lane >> 4) * 4;
    const int nlo = lane & 15;
#pragma unroll
    for (int ti = 0; ti < 4; ++ti)
#pragma unroll
        for (int tj = 0; tj < 4; ++tj) {
            const int mg = bm * 128 + m0 + ti * 16 + mlo;
            const int ng = bn * 128 + n0 + tj * 16 + nlo;
            float* dst = gdst + (size_t)mg * NG + ng;
#pragma unroll
            for (int r = 0; r < 4; ++r)
                dst[(size_t)r * NG] = acc[ti][tj][r];
        }
}

// ---------------------------------------------------------------------------
// Kernel 3: sum split-K partials + LSTM pointwise + MLP head + softmax +
// masked renorm. 256 threads/block; each wave handles 4 rows.
// ---------------------------------------------------------------------------
__global__ __launch_bounds__(256, 1) void lstm_mlp(
    const float* __restrict__ gpart, const float* __restrict__ bih,
    const float* __restrict__ bhh, const float* __restrict__ c0,
    const float* __restrict__ mask,
    const float* __restrict__ W1, const float* __restrict__ b1,
    const float* __restrict__ W2, const float* __restrict__ b2,
    const float* __restrict__ Wa, const float* __restrict__ ba,
    float* __restrict__ out) {
    __shared__ bf16 W1h[128 * 64];
    __shared__ bf16 W2h[64 * 128];
    __shared__ float Was[9 * 132];
    __shared__ float gb[512];
    __shared__ float b1s[64];
    __shared__ float b2s[128];
    __shared__ float bas[9];
    __shared__ float mws[4][4][12];

    const int t = threadIdx.x;
    for (int i = t; i < 64 * 128; i += 256) {
        const int j = i >> 7, d = i & 127;
        W1h[d * 64 + ((j + d) & 63)] = (bf16)W1[i];
    }
    for (int i = t; i < 128 * 64; i += 256) {
        const int r = i >> 6, j = i & 63;
        W2h[j * 128 + ((r + j) & 127)] = (bf16)W2[i];
    }
    for (int i = t; i < 9 * 128; i += 256) {
        const int a = i >> 7, d = i & 127;
        Was[a * 132 + d] = Wa[i];
    }
    for (int i = t; i < 512; i += 256) gb[i] = bih[i] + bhh[i];
    if (t < 64) b1s[t] = b1[t];
    if (t < 128) b2s[t] = b2[t];
    if (t < 9) bas[t] = ba[t];
    __syncthreads();

    const int wv = t >> 6, lane = t & 63;
    const int b0 = blockIdx.x * 16 + wv * 4;

    float h1a[4], h1b[4];
#pragma unroll
    for (int r = 0; r < 4; ++r) {
        const int b = b0 + r;
        // sum split-K partials: gv[q] = gates[b][q*64+lane]
        float gv[8];
#pragma unroll
        for (int q = 0; q < 8; ++q) gv[q] = gb[q * 64 + lane];
#pragma unroll
        for (int z = 0; z < SPLITK; ++z) {
            const float* gz = gpart + ((size_t)z * BATCH + b) * NG + lane;
#pragma unroll
            for (int q = 0; q < 8; ++q) gv[q] += gz[q * 64];
        }
        const float c01 = c0[(size_t)b * LH + lane];
        const float c02 = c0[(size_t)b * LH + 64 + lane];

        const float i1 = 1.f / (1.f + __expf(-gv[0]));
        const float i2 = 1.f / (1.f + __expf(-gv[1]));
        const float f1v = 1.f / (1.f + __expf(-gv[2]));
        const float f2v = 1.f / (1.f + __expf(-gv[3]));
        const float g1v = tanhf(gv[4]);
        const float g2v = tanhf(gv[5]);
        const float o1v = 1.f / (1.f + __expf(-gv[6]));
        const float o2v = 1.f / (1.f + __expf(-gv[7]));
        const float c11 = f1v * c01 + i1 * g1v;
        const float c12 = f2v * c02 + i2 * g2v;
        const float h11 = o1v * tanhf(c11);
        const float h12 = o2v * tanhf(c12);

        out[O_H1 + (size_t)b * LH + lane] = h11;
        out[O_H1 + (size_t)b * LH + 64 + lane] = h12;
        out[O_C1 + (size_t)b * LH + lane] = c11;
        out[O_C1 + (size_t)b * LH + 64 + lane] = c12;
        h1a[r] = h11;
        h1b[r] = h12;
        if (lane < 9) mws[wv][r][lane] = mask[(size_t)b * 9 + lane];
    }

    float u[4] = {b1s[lane], b1s[lane], b1s[lane], b1s[lane]};
#pragma unroll
    for (int d = 0; d < 64; ++d) {
        const float wv1 = (float)W1h[d * 64 + ((lane + d) & 63)];
        u[0] += rl(h1a[0], d) * wv1;
        u[1] += rl(h1a[1], d) * wv1;
        u[2] += rl(h1a[2], d) * wv1;
        u[3] += rl(h1a[3], d) * wv1;
    }
#pragma unroll
    for (int d = 64; d < 128; ++d) {
        const float wv1 = (float)W1h[d * 64 + ((lane + d) & 63)];
        u[0] += rl(h1b[0], d - 64) * wv1;
        u[1] += rl(h1b[1], d - 64) * wv1;
        u[2] += rl(h1b[2], d - 64) * wv1;
        u[3] += rl(h1b[3], d - 64) * wv1;
    }
#pragma unroll
    for (int r = 0; r < 4; ++r) u[r] = fmaxf(u[r], 0.f);

    float f1[4] = {b2s[lane], b2s[lane], b2s[lane], b2s[lane]};
    float f2[4] = {b2s[64 + lane], b2s[64 + lane], b2s[64 + lane], b2s[64 + lane]};
#pragma unroll
    for (int j = 0; j < 64; ++j) {
        const float w2a = (float)W2h[j * 128 + ((lane + j) & 127)];
        const float w2b = (float)W2h[j * 128 + ((64 + lane + j) & 127)];
#pragma unroll
        for (int r = 0; r < 4; ++r) {
            const float uj = rl(u[r], j);
            f1[r] += uj * w2a;
            f2[r] += uj * w2b;
        }
    }

    float p[4][9];
#pragma unroll
    for (int r = 0; r < 4; ++r)
#pragma unroll
        for (int a = 0; a < 9; ++a)
            p[r][a] = f1[r] * Was[a * 132 + lane] + f2[r] * Was[a * 132 + 64 + lane];
#pragma unroll
    for (int off = 1; off < 64; off <<= 1)
#pragma unroll
        for (int r = 0; r < 4; ++r)
#pragma unroll
            for (int a = 0; a < 9; ++a)
                p[r][a] += __shfl_xor(p[r][a], off, 64);

    asm volatile("s_waitcnt lgkmcnt(0)" ::: "memory");

#pragma unroll
    for (int r = 0; r < 4; ++r) {
        float lg[9], mx = -1e30f;
#pragma unroll
        for (int a = 0; a < 9; ++a) {
            lg[a] = p[r][a] + bas[a];
            mx = fmaxf(mx, lg[a]);
        }
        float es[9], tot = 0.f, ms = 0.f;
#pragma unroll
        for (int a = 0; a < 9; ++a) {
            es[a] = __expf(lg[a] - mx);
            tot += es[a];
            ms += es[a] * mws[wv][r][a];
        }
        const int b = b0 + r;
        if (lane < 9) {
            const float mv = mws[wv][r][lane];
            out[(size_t)b * 9 + lane] =
                (ms > 0.f) ? es[lane] * mv / ms : es[lane] / tot;
        }
    }
}

// ---------------------------------------------------------------------------
extern "C" void kernel_launch(void* const* d_in, const int* in_sizes, int n_in,
                              void* d_out, int out_size, void* d_ws, size_t ws_size,
                              hipStream_t stream) {
    const int* ab_ids = (const int*)d_in[0];
    const int* mv_ids = (const int*)d_in[1];
    const float* numerical = (const float*)d_in[2];
    const float* mask = (const float*)d_in[3];
    const float* h0 = (const float*)d_in[4];
    const float* c0 = (const float*)d_in[5];
    const float* ab_emb = (const float*)d_in[6];
    const float* mv_emb = (const float*)d_in[7];
    const float* numW = (const float*)d_in[8];
    const float* numb = (const float*)d_in[9];
    const float* Wih = (const float*)d_in[10];
    const float* Whh = (const float*)d_in[11];
    const float* bih = (const float*)d_in[12];
    const float* bhh = (const float*)d_in[13];
    const float* W1 = (const float*)d_in[14];
    const float* b1 = (const float*)d_in[15];
    const float* W2 = (const float*)d_in[16];
    const float* b2 = (const float*)d_in[17];
    const float* Wa = (const float*)d_in[18];
    const float* ba = (const float*)d_in[19];
    float* out = (float*)d_out;

    uint8_t* ws = (uint8_t*)d_ws;
    bf16* Wcat = (bf16*)(ws + OFF_WCAT);
    float* gpart = (float*)(ws + OFF_GPART);
    bf16* xtail = (bf16*)(ws + OFF_XT);
    bf16* ab8 = (bf16*)(ws + OFF_AB);
    bf16* mv8 = (bf16*)(ws + OFF_MV);
    uint32_t* addrs = (uint32_t*)(ws + OFF_ADDR);

    convert_w<<<512, 256, 0, stream>>>(Wih, Whh, Wcat);
    convert_emb<<<600, 256, 0, stream>>>(ab_emb, mv_emb, ab8, mv8);
    build_pre<<<BATCH, 256, 0, stream>>>(ab_ids, mv_ids, numerical, h0,
                                         numW, numb, xtail, addrs);
    gemm_gates<<<dim3(32, 4, 8), 256, 0, stream>>>(ws, Wcat, addrs, gpart);
    lstm_mlp<<<256, 256, 0, stream>>>(gpart, bih, bhh, c0, mask,
                                      W1, b1, W2, b2, Wa, ba, out);
}

// Round 7
// 190.688 us; speedup vs baseline: 1.3195x; 1.0993x over previous
//
#include <hip/hip_runtime.h>
#include <hip/hip_bf16.h>
#include <stdint.h>
#include <stddef.h>

typedef __bf16 bf16;
typedef __bf16 bf16x8 __attribute__((ext_vector_type(8)));
typedef float f32x4 __attribute__((ext_vector_type(4)));

#define BATCH 4096
#define KIH 7808          // Wih K
#define KTOT 7936         // 62 slots * 128 (h0 appended)
#define NG 512            // 4*LH gates
#define LH 128
#define HD 64
#define ED 128
#define SPLITK 4

// workspace layout (byte offsets)
#define OFF_WCAT 0u                 //  8,126,464  bf16 Wcat[512][7936]
#define OFF_GPART 8126464u          // 33,554,432  f32 gpart[4][4096][512]
#define OFF_XT   41680896u          //  2,097,152  bf16 xtail[4096][256]
#define OFF_AB   43778048u          //     76,800  bf16 ab8[300][128]
#define OFF_MV   43854848u          //    230,400  bf16 mv8[900][128]
#define OFF_ADDR 44085248u          //  2,097,152  u32 addrs[4096][64]
#define OFF_H1B  46182400u          //  1,048,576  bf16 h1b[4096][128]
// end: 47,230,976 B

// out layout: probs[B*9] | h1[B*128] | c1[B*128]
#define O_H1 (BATCH * 9)
#define O_C1 (BATCH * 9 + BATCH * LH)

// ---------------------------------------------------------------------------
typedef const __attribute__((address_space(1))) uint32_t* gas_ptr;
typedef __attribute__((address_space(3))) uint32_t* las_ptr;

__device__ __forceinline__ void async16(const void* g, void* l) {
    __builtin_amdgcn_global_load_lds((gas_ptr)g, (las_ptr)l, 16, 0, 0);
}

// ---------------------------------------------------------------------------
// Kernel 0a: pack fp32 [Wih | Whh] -> bf16 Wcat[512][7936]
// ---------------------------------------------------------------------------
__global__ void convert_w(const float* __restrict__ Wih,
                          const float* __restrict__ Whh,
                          bf16* __restrict__ Wcat) {
    const int n = blockIdx.x;           // 0..511
    const int t = threadIdx.x;          // 0..255
    const float* src_ih = Wih + (size_t)n * KIH;
    const float* src_hh = Whh + (size_t)n * LH;
    bf16* dst = Wcat + (size_t)n * KTOT;
    for (int k4 = t; k4 < KTOT / 4; k4 += 256) {
        const int k = k4 * 4;
        const float4 v = (k < KIH) ? *(const float4*)(src_ih + k)
                                   : *(const float4*)(src_hh + (k - KIH));
        bf16 o0 = (bf16)v.x, o1 = (bf16)v.y, o2 = (bf16)v.z, o3 = (bf16)v.w;
        dst[k] = o0; dst[k + 1] = o1; dst[k + 2] = o2; dst[k + 3] = o3;
    }
}

// ---------------------------------------------------------------------------
// Kernel 0b: fp32 embedding tables -> bf16 (L2-resident gather sources)
// ---------------------------------------------------------------------------
__global__ void convert_emb(const float* __restrict__ ab_emb,
                            const float* __restrict__ mv_emb,
                            bf16* __restrict__ ab8,
                            bf16* __restrict__ mv8) {
    const int i = blockIdx.x * 256 + threadIdx.x;   // 0..153599
    if (i < 300 * 128) ab8[i] = (bf16)ab_emb[i];
    else mv8[i - 300 * 128] = (bf16)mv_emb[i - 300 * 128];
}

// ---------------------------------------------------------------------------
// Kernel 0c: per-row slot offsets + xtail = [numproj | h0] (bf16)
// ---------------------------------------------------------------------------
__global__ void build_pre(const int* __restrict__ ab_ids,
                          const int* __restrict__ mv_ids,
                          const float* __restrict__ numerical,
                          const float* __restrict__ h0,
                          const float* __restrict__ numW,
                          const float* __restrict__ numb,
                          bf16* __restrict__ xtail,
                          uint32_t* __restrict__ addrs) {
    const int b = blockIdx.x;
    const int t = threadIdx.x;  // 0..255

    __shared__ int ids[60];
    __shared__ float numr[84];
    if (t < 60) ids[t] = (t < 12) ? ab_ids[b * 12 + t] : mv_ids[b * 48 + (t - 12)];
    if (t >= 128 && t < 128 + 84) numr[t - 128] = numerical[(size_t)b * 84 + (t - 128)];
    __syncthreads();

    if (t < 128) {
        float acc = numb[t];
#pragma unroll 4
        for (int k = 0; k < 84; ++k)
            acc += numr[k] * numW[t * 84 + k];
        xtail[(size_t)b * 256 + t] = (bf16)acc;
    } else {
        const int tt = t - 128;
        xtail[(size_t)b * 256 + 128 + tt] = (bf16)h0[(size_t)b * LH + tt];
    }

    if (t < 64) {
        uint32_t off;
        if (t < 12) off = OFF_AB + (uint32_t)ids[t] * 256u;
        else if (t < 60) off = OFF_MV + (uint32_t)ids[t] * 256u;
        else if (t == 60) off = OFF_XT + (uint32_t)b * 512u;
        else if (t == 61) off = OFF_XT + (uint32_t)b * 512u + 256u;
        else off = OFF_XT;  // unused slots 62,63
        addrs[(size_t)b * 64 + t] = off;
    }
}

// ---------------------------------------------------------------------------
// Kernel 2: gpart[bz] = x @ Wcat.T partial  (x gathered on the fly)
// 128x128 tile, BK=64, XOR-swizzled LDS, double-buffered, split-K=4,
// plain-store partials.
// ---------------------------------------------------------------------------
__global__ __launch_bounds__(256, 2) void gemm_gates(
    const uint8_t* __restrict__ wsbase,
    const bf16* __restrict__ Wcat,
    const uint32_t* __restrict__ addrs,
    float* __restrict__ gpart) {
    __shared__ bf16 As[2][128 * 64];    // 2 x 16 KB
    __shared__ bf16 Bs[2][128 * 64];    // 2 x 16 KB
    __shared__ uint32_t adr[17][128];   // 8.5 KB

    const int tid = threadIdx.x;
    const int w = tid >> 6;       // wave 0..3
    const int lane = tid & 63;
    const int bm = blockIdx.x;    // 0..31
    const int bn = blockIdx.y;    // 0..3
    const int bz = blockIdx.z;    // 0..3
    const int kt_beg = bz * 31;
    const int kt_end = kt_beg + 31;

    // preload this block's (row, slot) offsets
    const int s0 = kt_beg >> 1;
    const int ns = ((kt_end - 1) >> 1) - s0 + 1;   // <= 17
    for (int i = tid; i < ns * 128; i += 256) {
        adr[i >> 7][i & 127] =
            addrs[(size_t)(bm * 128 + (i & 127)) * 64 + s0 + (i >> 7)];
    }

    const int r_l = lane >> 3;                  // staging row within 8-row group
    const int sc16 = ((lane & 7) ^ r_l) * 16;   // XOR-swizzled 16B chunk (bytes)

    f32x4 acc[4][4];
#pragma unroll
    for (int i = 0; i < 4; ++i)
#pragma unroll
        for (int j = 0; j < 4; ++j)
#pragma unroll
            for (int r = 0; r < 4; ++r) acc[i][j][r] = 0.f;

    const int m0 = (w & 1) * 64;
    const int n0 = (w >> 1) * 64;

    __syncthreads();  // adr visible

    auto stage = [&](int kt, int pb) {
        const int k0 = kt * 64;
        const int sl = (kt >> 1) - s0;
        const int hb = (kt & 1) * 128;
#pragma unroll
        for (int j = 0; j < 4; ++j) {
            const int row = (w * 4 + j) * 8 + r_l;
            const uint8_t* gsrc = wsbase + adr[sl][row] + hb + sc16;
            async16(gsrc, (void*)&As[pb][((w * 4 + j) * 64 + lane) * 8]);
        }
#pragma unroll
        for (int j = 0; j < 4; ++j) {
            const int row = (w * 4 + j) * 8 + r_l;
            const bf16* gsrc = Wcat + (size_t)(bn * 128 + row) * KTOT + k0 + (sc16 >> 1);
            async16(gsrc, (void*)&Bs[pb][((w * 4 + j) * 64 + lane) * 8]);
        }
    };

    stage(kt_beg, 0);   // prologue into buffer 0

    for (int kt = kt_beg; kt < kt_end; ++kt) {
        const int pb = (kt - kt_beg) & 1;
        __syncthreads();
        if (kt + 1 < kt_end) stage(kt + 1, pb ^ 1);

        const bf16* Ab = &As[pb][0];
        const bf16* Bb = &Bs[pb][0];
#pragma unroll
        for (int ks = 0; ks < 2; ++ks) {
            bf16x8 af[4], bfr[4];
            const int kk8 = ks * 4 + (lane >> 4);       // global column chunk
#pragma unroll
            for (int t = 0; t < 4; ++t) {
                const int m = m0 + t * 16 + (lane & 15);
                af[t] = *(const bf16x8*)&Ab[m * 64 + ((kk8 ^ (m & 7)) * 8)];
                const int n = n0 + t * 16 + (lane & 15);
                bfr[t] = *(const bf16x8*)&Bb[n * 64 + ((kk8 ^ (n & 7)) * 8)];
            }
#pragma unroll
            for (int ti = 0; ti < 4; ++ti)
#pragma unroll
                for (int tj = 0; tj < 4; ++tj)
                    acc[ti][tj] = __builtin_amdgcn_mfma_f32_16x16x32_bf16(
                        af[ti], bfr[tj], acc[ti][tj], 0, 0, 0);
        }
    }

    // ---- epilogue: plain stores to this bz's partial buffer ----
    float* gdst = gpart + (size_t)bz * BATCH * NG;
    const int mlo = (lane >> 4) * 4;
    const int nlo = lane & 15;
#pragma unroll
    for (int ti = 0; ti < 4; ++ti)
#pragma unroll
        for (int tj = 0; tj < 4; ++tj) {
            const int mg = bm * 128 + m0 + ti * 16 + mlo;
            const int ng = bn * 128 + n0 + tj * 16 + nlo;
            float* dst = gdst + (size_t)mg * NG + ng;
#pragma unroll
            for (int r = 0; r < 4; ++r)
                dst[(size_t)r * NG] = acc[ti][tj][r];
        }
}

// ---------------------------------------------------------------------------
// Kernel 3: reduce split-K partials + LSTM pointwise.
// 2048 blocks x 256 threads; 2 rows/block, 1 thread per LSTM unit.
// Writes h1/c1 (fp32, d_out) and h1b (bf16 scratch for the MLP head).
// ---------------------------------------------------------------------------
__global__ void reduce_lstm(const float* __restrict__ gpart,
                            const float* __restrict__ bih,
                            const float* __restrict__ bhh,
                            const float* __restrict__ c0,
                            float* __restrict__ out,
                            bf16* __restrict__ h1b) {
    const int t = threadIdx.x;
    const int b = blockIdx.x * 2 + (t >> 7);
    const int u = t & 127;

    float gv[4];
#pragma unroll
    for (int q = 0; q < 4; ++q)
        gv[q] = bih[q * 128 + u] + bhh[q * 128 + u];
#pragma unroll
    for (int z = 0; z < SPLITK; ++z) {
        const float* gz = gpart + ((size_t)z * BATCH + b) * NG + u;
#pragma unroll
        for (int q = 0; q < 4; ++q) gv[q] += gz[q * 128];
    }

    const float iv = 1.f / (1.f + __expf(-gv[0]));
    const float fv = 1.f / (1.f + __expf(-gv[1]));
    const float gg = tanhf(gv[2]);
    const float ov = 1.f / (1.f + __expf(-gv[3]));
    const float c1 = fv * c0[(size_t)b * LH + u] + iv * gg;
    const float h1 = ov * tanhf(c1);

    out[O_H1 + (size_t)b * LH + u] = h1;
    out[O_C1 + (size_t)b * LH + u] = c1;
    h1b[(size_t)b * LH + u] = (bf16)h1;
}

// ---------------------------------------------------------------------------
// Kernel 4: MLP head via chained MFMA (h1->u->feat->logits) + softmax +
// masked renorm. 128 blocks x 128 threads (2 waves); 1 wave = 16 rows.
// Weights staged once per block into LDS in MFMA-B-fragment order (bf16).
// ---------------------------------------------------------------------------
__global__ __launch_bounds__(128, 2) void mlp_head(
    const bf16* __restrict__ h1b, const float* __restrict__ mask,
    const float* __restrict__ W1, const float* __restrict__ b1,
    const float* __restrict__ W2, const float* __restrict__ b2,
    const float* __restrict__ Wa, const float* __restrict__ ba,
    float* __restrict__ out) {
    __shared__ bf16 W1f[8192];    // 16 frags (nt<4,kt<4): [(nt*4+kt)*64+lane]*8+j
    __shared__ bf16 W2f[8192];    // 16 frags (nt<8,kt<2): [(nt*2+kt)*64+lane]*8+j
    __shared__ bf16 Waf[2048];    // 4 frags (kt<4)
    __shared__ bf16 uS[2][16 * 64];
    __shared__ bf16 fS[2][16 * 128];
    __shared__ float b1s[64];
    __shared__ float b2s[128];
    __shared__ float bas[16];

    const int tid = threadIdx.x;
    // ---- stage weights as B-fragments: B[n][k], lane holds n=l&15, k=(l>>4)*8+j
    for (int e = tid; e < 8192; e += 128) {     // W1 (64x128): u[n]=Σ h1[k]W1[n][k]
        const int j = e & 7, ln = (e >> 3) & 63, fid = e >> 9;
        const int kt = fid & 3, nt = fid >> 2;
        const int n = nt * 16 + (ln & 15);
        const int k = kt * 32 + (ln >> 4) * 8 + j;
        W1f[e] = (bf16)W1[n * 128 + k];
    }
    for (int e = tid; e < 8192; e += 128) {     // W2 (128x64)
        const int j = e & 7, ln = (e >> 3) & 63, fid = e >> 9;
        const int kt = fid & 1, nt = fid >> 1;
        const int n = nt * 16 + (ln & 15);
        const int k = kt * 32 + (ln >> 4) * 8 + j;
        W2f[e] = (bf16)W2[n * 64 + k];
    }
    for (int e = tid; e < 2048; e += 128) {     // Wa (9x128, zero-padded to 16)
        const int j = e & 7, ln = (e >> 3) & 63, kt = e >> 9;
        const int n = ln & 15;
        const int k = kt * 32 + (ln >> 4) * 8 + j;
        Waf[e] = (n < 9) ? (bf16)Wa[n * 128 + k] : (bf16)0.f;
    }
    if (tid < 64) b1s[tid] = b1[tid];
    if (tid < 16) bas[tid] = (tid < 9) ? ba[tid] : 0.f;
    {
        const int i = tid;
        if (i < 128) b2s[i] = b2[i];
    }
    __syncthreads();

    const int wv = tid >> 6, lane = tid & 63;
    const int mt = blockIdx.x * 2 + wv;     // m-tile 0..255
    const int mrow0 = mt * 16;
    const int nl = lane & 15, kg = lane >> 4;

    // ---- A-frags of h1 tile (16x128) ----
    bf16x8 ah[4];
#pragma unroll
    for (int kt = 0; kt < 4; ++kt)
        ah[kt] = *(const bf16x8*)&h1b[(size_t)(mrow0 + nl) * 128 + kt * 32 + kg * 8];

    // ---- stage 1: u = relu(h1 @ W1^T + b1)  (16x64) ----
#pragma unroll
    for (int nt = 0; nt < 4; ++nt) {
        f32x4 a = {0.f, 0.f, 0.f, 0.f};
#pragma unroll
        for (int kt = 0; kt < 4; ++kt)
            a = __builtin_amdgcn_mfma_f32_16x16x32_bf16(
                ah[kt], *(const bf16x8*)&W1f[((nt * 4 + kt) * 64 + lane) * 8], a, 0, 0, 0);
        const int n = nt * 16 + nl;
#pragma unroll
        for (int r = 0; r < 4; ++r)
            uS[wv][(kg * 4 + r) * 64 + n] = (bf16)fmaxf(a[r] + b1s[n], 0.f);
    }

    bf16x8 au[2];
#pragma unroll
    for (int kt = 0; kt < 2; ++kt)
        au[kt] = *(const bf16x8*)&uS[wv][nl * 64 + kt * 32 + kg * 8];

    // ---- stage 2: feat = u @ W2^T + b2  (16x128) ----
#pragma unroll
    for (int nt = 0; nt < 8; ++nt) {
        f32x4 a = {0.f, 0.f, 0.f, 0.f};
#pragma unroll
        for (int kt = 0; kt < 2; ++kt)
            a = __builtin_amdgcn_mfma_f32_16x16x32_bf16(
                au[kt], *(const bf16x8*)&W2f[((nt * 2 + kt) * 64 + lane) * 8], a, 0, 0, 0);
        const int n = nt * 16 + nl;
#pragma unroll
        for (int r = 0; r < 4; ++r)
            fS[wv][(kg * 4 + r) * 128 + n] = (bf16)(a[r] + b2s[n]);
    }

    bf16x8 afr[4];
#pragma unroll
    for (int kt = 0; kt < 4; ++kt)
        afr[kt] = *(const bf16x8*)&fS[wv][nl * 128 + kt * 32 + kg * 8];

    // ---- stage 3: logits = feat @ Wa^T + ba  (16x16, 9 valid) ----
    f32x4 lg4 = {0.f, 0.f, 0.f, 0.f};
#pragma unroll
    for (int kt = 0; kt < 4; ++kt)
        lg4 = __builtin_amdgcn_mfma_f32_16x16x32_bf16(
            afr[kt], *(const bf16x8*)&Waf[(kt * 64 + lane) * 8], lg4, 0, 0, 0);

    // ---- softmax + masked renorm; row m = kg*4+r, action a = nl ----
#pragma unroll
    for (int r = 0; r < 4; ++r) {
        const int b = mrow0 + kg * 4 + r;
        float lg = (nl < 9) ? lg4[r] + bas[nl] : -1e30f;
        float mx = lg;
#pragma unroll
        for (int off = 1; off < 16; off <<= 1)
            mx = fmaxf(mx, __shfl_xor(mx, off, 64));
        const float e = (nl < 9) ? __expf(lg - mx) : 0.f;
        const float mv = (nl < 9) ? mask[(size_t)b * 9 + nl] : 0.f;
        float tot = e, ms = e * mv;
#pragma unroll
        for (int off = 1; off < 16; off <<= 1) {
            tot += __shfl_xor(tot, off, 64);
            ms += __shfl_xor(ms, off, 64);
        }
        if (nl < 9)
            out[(size_t)b * 9 + nl] = (ms > 0.f) ? e * mv / ms : e / tot;
    }
}

// ---------------------------------------------------------------------------
extern "C" void kernel_launch(void* const* d_in, const int* in_sizes, int n_in,
                              void* d_out, int out_size, void* d_ws, size_t ws_size,
                              hipStream_t stream) {
    const int* ab_ids = (const int*)d_in[0];
    const int* mv_ids = (const int*)d_in[1];
    const float* numerical = (const float*)d_in[2];
    const float* mask = (const float*)d_in[3];
    const float* h0 = (const float*)d_in[4];
    const float* c0 = (const float*)d_in[5];
    const float* ab_emb = (const float*)d_in[6];
    const float* mv_emb = (const float*)d_in[7];
    const float* numW = (const float*)d_in[8];
    const float* numb = (const float*)d_in[9];
    const float* Wih = (const float*)d_in[10];
    const float* Whh = (const float*)d_in[11];
    const float* bih = (const float*)d_in[12];
    const float* bhh = (const float*)d_in[13];
    const float* W1 = (const float*)d_in[14];
    const float* b1 = (const float*)d_in[15];
    const float* W2 = (const float*)d_in[16];
    const float* b2 = (const float*)d_in[17];
    const float* Wa = (const float*)d_in[18];
    const float* ba = (const float*)d_in[19];
    float* out = (float*)d_out;

    uint8_t* ws = (uint8_t*)d_ws;
    bf16* Wcat = (bf16*)(ws + OFF_WCAT);
    float* gpart = (float*)(ws + OFF_GPART);
    bf16* xtail = (bf16*)(ws + OFF_XT);
    bf16* ab8 = (bf16*)(ws + OFF_AB);
    bf16* mv8 = (bf16*)(ws + OFF_MV);
    uint32_t* addrs = (uint32_t*)(ws + OFF_ADDR);
    bf16* h1b = (bf16*)(ws + OFF_H1B);

    convert_w<<<512, 256, 0, stream>>>(Wih, Whh, Wcat);
    convert_emb<<<600, 256, 0, stream>>>(ab_emb, mv_emb, ab8, mv8);
    build_pre<<<BATCH, 256, 0, stream>>>(ab_ids, mv_ids, numerical, h0,
                                         numW, numb, xtail, addrs);
    gemm_gates<<<dim3(32, 4, SPLITK), 256, 0, stream>>>(ws, Wcat, addrs, gpart);
    reduce_lstm<<<BATCH / 2, 256, 0, stream>>>(gpart, bih, bhh, c0, out, h1b);
    mlp_head<<<128, 128, 0, stream>>>(h1b, mask, W1, b1, W2, b2, Wa, ba, out);
}